// Round 2
// baseline (224.027 us; speedup 1.0000x reference)
//
#include <hip/hip_runtime.h>
#include <hip/hip_bf16.h>

#define N_NODES 50000
#define N_EDGES 800000
#define D 128
#define ALPHA 0.2f
#define NEG_INF -1e30f

#define KB_BLOCKS 3125                 // 1 edge per thread, exact (3125*256)
#define LDS_STRIDE 272                 // 16 rows x (256B + 16B pad)

// scan geometry: one 1024-thread block scans deg alone, 52 elems/thread
#define SCAN_PER 52
#define SCAN_PAD (1024 * SCAN_PER)     // 53248 >= N_NODES, zero-padded
// m/s geometry: 1024 threads/block over edges
#define NB_MS ((N_EDGES + 1023) / 1024)  // 782

typedef __attribute__((ext_vector_type(8))) short short8;
typedef __attribute__((ext_vector_type(4))) float floatx4;

__device__ __forceinline__ unsigned int f2bf(float v)
{
    __hip_bfloat16 b = __float2bfloat16(v);
    return (unsigned int)*reinterpret_cast<unsigned short*>(&b);
}
__device__ __forceinline__ float bf_lo(unsigned int u)
{
    return __uint_as_float(u << 16);
}
__device__ __forceinline__ float bf_hi(unsigned int u)
{
    return __uint_as_float(u & 0xFFFF0000u);
}

// ---- K0: zero deg (padded region, so the scan kernel needs no load guards)
__global__ __launch_bounds__(1024) void k_zero(int* __restrict__ deg)
{
    deg[blockIdx.x * 1024 + threadIdx.x] = 0;
}

// ---- K1: fused per-16-row-tile kernel, 3125 blocks (exact):
//   (w) per-block redundant w12 = {W@a1, W@a2} into LDS (kills the k_prep
//       dependency; W rows are L1/L2-hot — reread is cheap)
//   (a) load x tile fp32, exact s1/s2 (16-lane xor-reduce), bf16 -> LDS
//   (b) per-wave B frags from W, even/odd column split
//   (c) 8x MFMA 16x16x32 bf16, packed u32 stores of hb
//   (d) deg count + per-edge rank (atomic return), 1 edge per thread
__global__ __launch_bounds__(256) void k_fused(
    const float* __restrict__ x, const float* __restrict__ W,
    const float* __restrict__ a, const int* __restrict__ ei,
    unsigned short* __restrict__ hb, float* __restrict__ s1,
    float* __restrict__ s2, int* __restrict__ deg, int* __restrict__ rank)
{
    __shared__ unsigned char lds[16 * LDS_STRIDE];
    __shared__ float w12s[2 * D];
    const int t = threadIdx.x;
    const int rowbase = blockIdx.x * 16;

    // (w) thread t computes w12[t>>7][t&127] — same summation order as the
    // old k_prep (bitwise-compatible numerics)
    {
        const int wr_ = t & 127;
        const int which = t >> 7;
        const float* av = a + which * D;
        const float* wrow = W + (size_t)wr_ * D;
        float acc = 0.f;
        #pragma unroll 8
        for (int j = 0; j < D; ++j)
            acc += wrow[j] * av[j];
        w12s[which * D + wr_] = acc;
    }

    // (a) stage x: thread t -> row r=t>>4, col-group c=t&15 (8 cols)
    const int r = t >> 4;
    const int c = t & 15;
    const float* xp = x + (size_t)(rowbase + r) * D + c * 8;
    const float4 v0 = *(const float4*)(xp);
    const float4 v1 = *(const float4*)(xp + 4);

    // (b) B frags — issue independent of staging loads
    const int lane = t & 63;
    const int wv = t >> 6;
    const int q = lane >> 4;
    const int nIdx = lane & 15;
    const int n0 = wv * 32;
    short8 B[2][4];
    #pragma unroll
    for (int kt = 0; kt < 4; ++kt) {
        short8 be, bo;
        #pragma unroll
        for (int j = 0; j < 8; ++j) {
            const float* wp = W + (size_t)(kt * 32 + q * 8 + j) * D + n0 + 2 * nIdx;
            be[j] = (short)f2bf(wp[0]);
            bo[j] = (short)f2bf(wp[1]);
        }
        B[0][kt] = be;
        B[1][kt] = bo;
    }

    __syncthreads();    // w12s ready

    // (a cont.) s1/s2 exact fp32 partials + bf16 pack to LDS
    {
        const float* w1 = w12s + c * 8;
        const float* w2 = w12s + D + c * 8;
        float p1 = v0.x * w1[0] + v0.y * w1[1] + v0.z * w1[2] + v0.w * w1[3]
                 + v1.x * w1[4] + v1.y * w1[5] + v1.z * w1[6] + v1.w * w1[7];
        float p2 = v0.x * w2[0] + v0.y * w2[1] + v0.z * w2[2] + v0.w * w2[3]
                 + v1.x * w2[4] + v1.y * w2[5] + v1.z * w2[6] + v1.w * w2[7];
        #pragma unroll
        for (int mask = 8; mask >= 1; mask >>= 1) {
            p1 += __shfl_xor(p1, mask);
            p2 += __shfl_xor(p2, mask);
        }
        if (c == 0) { s1[rowbase + r] = p1; s2[rowbase + r] = p2; }

        uint4 pk;
        pk.x = f2bf(v0.x) | (f2bf(v0.y) << 16);
        pk.y = f2bf(v0.z) | (f2bf(v0.w) << 16);
        pk.z = f2bf(v1.x) | (f2bf(v1.y) << 16);
        pk.w = f2bf(v1.z) | (f2bf(v1.w) << 16);
        *(uint4*)(lds + r * LDS_STRIDE + c * 16) = pk;
    }
    __syncthreads();

    // (c) A frags from LDS: A[m=nIdx][k=kt*32+q*8+j] -> byte kt*64 + q*16
    const unsigned char* ab = lds + nIdx * LDS_STRIDE + q * 16;
    const short8 A0 = *(const short8*)(ab);
    const short8 A1 = *(const short8*)(ab + 64);
    const short8 A2 = *(const short8*)(ab + 128);
    const short8 A3 = *(const short8*)(ab + 192);

    floatx4 acc0 = {0.f, 0.f, 0.f, 0.f};
    floatx4 acc1 = {0.f, 0.f, 0.f, 0.f};
    acc0 = __builtin_amdgcn_mfma_f32_16x16x32_bf16(A0, B[0][0], acc0, 0, 0, 0);
    acc1 = __builtin_amdgcn_mfma_f32_16x16x32_bf16(A0, B[1][0], acc1, 0, 0, 0);
    acc0 = __builtin_amdgcn_mfma_f32_16x16x32_bf16(A1, B[0][1], acc0, 0, 0, 0);
    acc1 = __builtin_amdgcn_mfma_f32_16x16x32_bf16(A1, B[1][1], acc1, 0, 0, 0);
    acc0 = __builtin_amdgcn_mfma_f32_16x16x32_bf16(A2, B[0][2], acc0, 0, 0, 0);
    acc1 = __builtin_amdgcn_mfma_f32_16x16x32_bf16(A2, B[1][2], acc1, 0, 0, 0);
    acc0 = __builtin_amdgcn_mfma_f32_16x16x32_bf16(A3, B[0][3], acc0, 0, 0, 0);
    acc1 = __builtin_amdgcn_mfma_f32_16x16x32_bf16(A3, B[1][3], acc1, 0, 0, 0);

    // epilogue: acc0 = even col n0+2*nIdx, acc1 = odd col n0+2*nIdx+1
    #pragma unroll
    for (int i = 0; i < 4; ++i) {
        const int row = rowbase + q * 4 + i;
        const unsigned int pk = f2bf(acc0[i]) | (f2bf(acc1[i]) << 16);
        *(unsigned int*)(hb + (size_t)row * D + n0 + 2 * nIdx) = pk;
    }

    // (d) deg + rank: exactly one edge per thread (3125*256 == N_EDGES)
    const int e = blockIdx.x * 256 + t;
    rank[e] = atomicAdd(&deg[ei[N_EDGES + e]], 1);
}

__device__ __forceinline__ void online_combine(float& m, float& s,
                                               float om, float os)
{
    float nm = fmaxf(m, om);
    s = s * __expf(m - nm) + os * __expf(om - nm);
    m = nm;
}

// ---- K2 (heterogeneous): block 0 = full exclusive scan of deg -> offs
// (1024 threads x 52 elems, int4, zero-padded so no guards); blocks 1..NB_MS
// = per-block online-softmax (m,s) over edges (independent of the scan —
// previously serialized behind it inside k_bucket).
__global__ __launch_bounds__(1024) void k_mid(
    const int* __restrict__ ei, const float* __restrict__ s1,
    const float* __restrict__ s2, const int* __restrict__ deg,
    int* __restrict__ offs, float* __restrict__ bm, float* __restrict__ bs)
{
    const int t = threadIdx.x;
    const int lane = t & 63;
    const int wv = t >> 6;

    if (blockIdx.x == 0) {
        // ---- the whole scan on one block
        __shared__ int wsum[16];
        const int base = t * SCAN_PER;
        int4 v[13];
        const int4* dp = (const int4*)(deg + base);
        int s = 0;
        #pragma unroll
        for (int k = 0; k < 13; ++k) {
            v[k] = dp[k];
            s += v[k].x + v[k].y + v[k].z + v[k].w;
        }
        // wave-inclusive scan of per-thread sums
        int inc = s;
        #pragma unroll
        for (int off = 1; off < 64; off <<= 1) {
            int u = __shfl_up(inc, off);
            if (lane >= off) inc += u;
        }
        if (lane == 63) wsum[wv] = inc;
        __syncthreads();
        if (wv == 0 && lane < 16) {
            int wval = wsum[lane];
            int winc = wval;
            #pragma unroll
            for (int off = 1; off < 16; off <<= 1) {
                int u = __shfl_up(winc, off);
                if (lane >= off) winc += u;
            }
            wsum[lane] = winc - wval;   // exclusive wave offset
        }
        __syncthreads();
        int run = wsum[wv] + (inc - s);  // exclusive thread prefix
        int4* op = (int4*)(offs + base);
        #pragma unroll
        for (int k = 0; k < 13; ++k) {
            int4 o;
            o.x = run;             run += v[k].x;
            o.y = run;             run += v[k].y;
            o.z = run;             run += v[k].z;
            o.w = run;             run += v[k].w;
            op[k] = o;
        }
        // offs[N_NODES] (== N_EDGES) falls inside the padded range: the pad
        // degs are zero, so offs[50000] == total. Nothing more to do.
        return;
    }

    // ---- (m,s) over edges, 1024 threads/block
    const int e = (blockIdx.x - 1) * 1024 + t;
    float m = NEG_INF, s = 0.f;
    if (e < N_EDGES) {
        const int sN = ei[e];
        const int dN = ei[N_EDGES + e];
        float vv = s1[sN] + s2[dN];
        vv = vv > 0.f ? vv : ALPHA * vv;
        m = vv;
        s = 1.f;
    }
    #pragma unroll
    for (int off = 32; off >= 1; off >>= 1) {
        float om = __shfl_down(m, off);
        float os = __shfl_down(s, off);
        online_combine(m, s, om, os);
    }
    __shared__ float rm[16], rs[16];
    if (lane == 0) { rm[wv] = m; rs[wv] = s; }
    __syncthreads();
    if (t == 0) {
        #pragma unroll
        for (int w = 1; w < 16; ++w) online_combine(m, s, rm[w], rs[w]);
        bm[blockIdx.x - 1] = m;
        bs[blockIdx.x - 1] = s;
    }
}

// ---- K3: atomic-free CSR scatter (pos = offs[dst] + rank[e]); block 0
// additionally folds the NB_MS (m,s) partials -> global MZ (absorbs the
// old k_reduce_mz dispatch).
__global__ __launch_bounds__(256) void k_post(
    const int* __restrict__ ei, const int* __restrict__ offs,
    const int* __restrict__ rank, unsigned int* __restrict__ csr,
    const float* __restrict__ bm, const float* __restrict__ bs,
    float* __restrict__ MZ)
{
    const int e = blockIdx.x * 256 + threadIdx.x;
    const int sN = ei[e];
    const int dN = ei[N_EDGES + e];
    csr[offs[dN] + rank[e]] = (unsigned int)sN;

    if (blockIdx.x == 0) {
        float m = NEG_INF, s = 0.f;
        for (int i = threadIdx.x; i < NB_MS; i += 256)
            online_combine(m, s, bm[i], bs[i]);
        #pragma unroll
        for (int off = 32; off >= 1; off >>= 1) {
            float om = __shfl_down(m, off);
            float os = __shfl_down(s, off);
            online_combine(m, s, om, os);
        }
        __shared__ float rm[4], rs[4];
        const int wid = threadIdx.x >> 6;
        if ((threadIdx.x & 63) == 0) { rm[wid] = m; rs[wid] = s; }
        __syncthreads();
        if (threadIdx.x == 0) {
            #pragma unroll
            for (int w = 1; w < 4; ++w) online_combine(m, s, rm[w], rs[w]);
            MZ[0] = m;
            MZ[1] = s;
        }
    }
}

// ---- K4: one wave per dst node; lane loads ONE csr src (coalesced),
// recomputes exact fp32 score + ONE exp; inner loop broadcasts (src, att)
// via uniform-index shfl with 8 independent hb row loads in flight.
__global__ __launch_bounds__(256) void k_gather(
    const unsigned int* __restrict__ csr, const int* __restrict__ offs,
    const float* __restrict__ s1, const float* __restrict__ s2,
    const unsigned short* __restrict__ hb, const float* __restrict__ MZ,
    float* __restrict__ out)
{
    const int node = (blockIdx.x * blockDim.x + threadIdx.x) >> 6;
    if (node >= N_NODES) return;
    const int lane = threadIdx.x & 63;
    const float M = MZ[0];
    const float invZ = 1.0f / MZ[1];
    const float s2n = s2[node];
    const int beg = offs[node];
    const int end = offs[node + 1];

    float a0 = 0.f, a1 = 0.f, b0 = 0.f, b1 = 0.f;
    float c0 = 0.f, c1 = 0.f, d0 = 0.f, d1 = 0.f;
    float e0 = 0.f, e1 = 0.f, f0 = 0.f, f1 = 0.f;
    float g0 = 0.f, g1 = 0.f, h0 = 0.f, h1 = 0.f;

    for (int cb = beg; cb < end; cb += 64) {
        const int n = min(64, end - cb);
        const int srcl = (cb + lane < end) ? (int)csr[cb + lane] : 0;
        float v = s1[srcl] + s2n;
        v = v > 0.f ? v : ALPHA * v;
        const float attl = __expf(v - M) * invZ;

        int j = 0;
        for (; j + 7 < n; j += 8) {
            const int i0 = __shfl(srcl, j);
            const int i1 = __shfl(srcl, j + 1);
            const int i2 = __shfl(srcl, j + 2);
            const int i3 = __shfl(srcl, j + 3);
            const int i4 = __shfl(srcl, j + 4);
            const int i5 = __shfl(srcl, j + 5);
            const int i6 = __shfl(srcl, j + 6);
            const int i7 = __shfl(srcl, j + 7);
            const float w0 = __shfl(attl, j);
            const float w1 = __shfl(attl, j + 1);
            const float w2 = __shfl(attl, j + 2);
            const float w3 = __shfl(attl, j + 3);
            const float w4 = __shfl(attl, j + 4);
            const float w5 = __shfl(attl, j + 5);
            const float w6 = __shfl(attl, j + 6);
            const float w7 = __shfl(attl, j + 7);
            const unsigned int u0 = *(const unsigned int*)(hb + (size_t)i0 * D + lane * 2);
            const unsigned int u1 = *(const unsigned int*)(hb + (size_t)i1 * D + lane * 2);
            const unsigned int u2 = *(const unsigned int*)(hb + (size_t)i2 * D + lane * 2);
            const unsigned int u3 = *(const unsigned int*)(hb + (size_t)i3 * D + lane * 2);
            const unsigned int u4 = *(const unsigned int*)(hb + (size_t)i4 * D + lane * 2);
            const unsigned int u5 = *(const unsigned int*)(hb + (size_t)i5 * D + lane * 2);
            const unsigned int u6 = *(const unsigned int*)(hb + (size_t)i6 * D + lane * 2);
            const unsigned int u7 = *(const unsigned int*)(hb + (size_t)i7 * D + lane * 2);
            a0 += w0 * bf_lo(u0); a1 += w0 * bf_hi(u0);
            b0 += w1 * bf_lo(u1); b1 += w1 * bf_hi(u1);
            c0 += w2 * bf_lo(u2); c1 += w2 * bf_hi(u2);
            d0 += w3 * bf_lo(u3); d1 += w3 * bf_hi(u3);
            e0 += w4 * bf_lo(u4); e1 += w4 * bf_hi(u4);
            f0 += w5 * bf_lo(u5); f1 += w5 * bf_hi(u5);
            g0 += w6 * bf_lo(u6); g1 += w6 * bf_hi(u6);
            h0 += w7 * bf_lo(u7); h1 += w7 * bf_hi(u7);
        }
        for (; j + 3 < n; j += 4) {
            const int i0 = __shfl(srcl, j);
            const int i1 = __shfl(srcl, j + 1);
            const int i2 = __shfl(srcl, j + 2);
            const int i3 = __shfl(srcl, j + 3);
            const float w0 = __shfl(attl, j);
            const float w1 = __shfl(attl, j + 1);
            const float w2 = __shfl(attl, j + 2);
            const float w3 = __shfl(attl, j + 3);
            const unsigned int u0 = *(const unsigned int*)(hb + (size_t)i0 * D + lane * 2);
            const unsigned int u1 = *(const unsigned int*)(hb + (size_t)i1 * D + lane * 2);
            const unsigned int u2 = *(const unsigned int*)(hb + (size_t)i2 * D + lane * 2);
            const unsigned int u3 = *(const unsigned int*)(hb + (size_t)i3 * D + lane * 2);
            a0 += w0 * bf_lo(u0); a1 += w0 * bf_hi(u0);
            b0 += w1 * bf_lo(u1); b1 += w1 * bf_hi(u1);
            c0 += w2 * bf_lo(u2); c1 += w2 * bf_hi(u2);
            d0 += w3 * bf_lo(u3); d1 += w3 * bf_hi(u3);
        }
        for (; j < n; ++j) {
            const int i0 = __shfl(srcl, j);
            const float w0 = __shfl(attl, j);
            const unsigned int u0 = *(const unsigned int*)(hb + (size_t)i0 * D + lane * 2);
            a0 += w0 * bf_lo(u0); a1 += w0 * bf_hi(u0);
        }
    }
    float2 r;
    r.x = ((a0 + b0) + (c0 + d0)) + ((e0 + f0) + (g0 + h0));
    r.y = ((a1 + b1) + (c1 + d1)) + ((e1 + f1) + (g1 + h1));
    *(float2*)(out + (size_t)node * D + lane * 2) = r;
}

extern "C" void kernel_launch(void* const* d_in, const int* in_sizes, int n_in,
                              void* d_out, int out_size, void* d_ws, size_t ws_size,
                              hipStream_t stream)
{
    const float* x = (const float*)d_in[0];
    const float* W = (const float*)d_in[1];
    const float* a = (const float*)d_in[2];
    const int* ei = (const int*)d_in[3];
    float* out = (float*)d_out;

    char* wsb = (char*)d_ws;
    unsigned int* csr = (unsigned int*)wsb;                        // 3.2 MB
    unsigned short* hb = (unsigned short*)(wsb + (size_t)N_EDGES * 4); // 12.8 MB
    int* rank     = (int*)((char*)hb + (size_t)N_NODES * D * 2);   // 3.2 MB
    float* s1     = (float*)(rank + N_EDGES);                      // 50,000
    float* s2     = s1 + N_NODES;                                  // 50,000
    int*   deg    = (int*)(s2 + N_NODES);                          // SCAN_PAD (zero-padded)
    int*   offs   = deg + SCAN_PAD;                                // SCAN_PAD (covers N_NODES+1)
    float* bm     = (float*)(offs + SCAN_PAD);                     // NB_MS
    float* bs     = bm + NB_MS;                                    // NB_MS
    float* MZ     = bs + NB_MS;                                    // 2

    k_zero<<<SCAN_PAD / 1024, 1024, 0, stream>>>(deg);
    k_fused<<<N_NODES / 16, 256, 0, stream>>>(x, W, a, ei, hb, s1, s2,
                                              deg, rank);
    k_mid<<<NB_MS + 1, 1024, 0, stream>>>(ei, s1, s2, deg, offs, bm, bs);
    k_post<<<KB_BLOCKS, 256, 0, stream>>>(ei, offs, rank, csr, bm, bs, MZ);
    k_gather<<<(N_NODES * 64 + 255) / 256, 256, 0, stream>>>(
        csr, offs, s1, s2, hb, MZ, out);
}

// Round 3
// 182.415 us; speedup vs baseline: 1.2281x; 1.2281x over previous
//
#include <hip/hip_runtime.h>
#include <hip/hip_bf16.h>

#define N_NODES 50000
#define N_EDGES 800000
#define D 128
#define ALPHA 0.2f
#define NEG_INF -1e30f

#define KB_BLOCKS 3125                 // 1 edge per thread, exact (3125*256)
#define LDS_STRIDE 272                 // 16 rows x (256B + 16B pad)

// scan geometry: one 1024-thread block scans deg alone, 52 elems/thread
#define SCAN_PER 52
#define SCAN_PAD (1024 * SCAN_PER)     // 53248 >= N_NODES, zero-padded
// m/s geometry: 1024 threads/block over edges
#define NB_MS ((N_EDGES + 1023) / 1024)  // 782

typedef __attribute__((ext_vector_type(8))) short short8;
typedef __attribute__((ext_vector_type(4))) float floatx4;

__device__ __forceinline__ unsigned int f2bf(float v)
{
    __hip_bfloat16 b = __float2bfloat16(v);
    return (unsigned int)*reinterpret_cast<unsigned short*>(&b);
}
__device__ __forceinline__ float bf_lo(unsigned int u)
{
    return __uint_as_float(u << 16);
}
__device__ __forceinline__ float bf_hi(unsigned int u)
{
    return __uint_as_float(u & 0xFFFF0000u);
}

// ---- K0: zero deg (padded, so the scan needs no guards); block 0 computes
// w12 = {W@a1, W@a2} ONCE; block 1 pre-packs W into the bf16 B-fragment
// layout wb (32 KB) so k_fused's 3125 blocks never touch W again.
// wb[f]: f = (((wv*4 + kt)*2 + half)*64 + lane)*8 + j
//   -> bf16( W[(kt*32 + (lane>>4)*8 + j)*D + wv*32 + 2*(lane&15) + half] )
__global__ __launch_bounds__(1024) void k_prep(
    const float* __restrict__ W, const float* __restrict__ a,
    float* __restrict__ w12, unsigned short* __restrict__ wb,
    int* __restrict__ deg)
{
    const int t = threadIdx.x;
    deg[blockIdx.x * 1024 + t] = 0;

    if (blockIdx.x == 0 && t < 256) {
        const int r = t & 127;
        const int which = t >> 7;
        const float* av = a + which * D;
        float acc = 0.f;
        #pragma unroll 8
        for (int j = 0; j < D; ++j)
            acc += W[(size_t)r * D + j] * av[j];
        w12[which * D + r] = acc;
    }
    if (blockIdx.x == 1) {
        #pragma unroll
        for (int k = 0; k < 16; ++k) {
            const int f = t * 16 + k;
            const int j    = f & 7;
            const int lane = (f >> 3) & 63;
            const int half = (f >> 9) & 1;
            const int kt   = (f >> 10) & 3;
            const int wv   = f >> 12;
            const int q    = lane >> 4;
            const int nIdx = lane & 15;
            const float val =
                W[(size_t)(kt * 32 + q * 8 + j) * D + wv * 32 + 2 * nIdx + half];
            wb[f] = (unsigned short)f2bf(val);
        }
    }
}

// ---- K1: fused per-16-row-tile kernel, 3125 blocks (exact):
//   (a) load x tile fp32, exact s1/s2 (16-lane xor-reduce), bf16 -> LDS
//   (b) B frags: 8x coalesced short8 loads from pre-packed wb (L2-resident)
//   (c) 8x MFMA 16x16x32 bf16, packed u32 stores of hb
//   (d) deg count + per-edge rank (atomic return), 1 edge per thread
__global__ __launch_bounds__(256) void k_fused(
    const float* __restrict__ x, const float* __restrict__ w12,
    const unsigned short* __restrict__ wb, const int* __restrict__ ei,
    unsigned short* __restrict__ hb, float* __restrict__ s1,
    float* __restrict__ s2, int* __restrict__ deg, int* __restrict__ rank)
{
    __shared__ unsigned char lds[16 * LDS_STRIDE];
    const int t = threadIdx.x;
    const int rowbase = blockIdx.x * 16;

    // (a) stage x: thread t -> row r=t>>4, col-group c=t&15 (8 cols)
    const int r = t >> 4;
    const int c = t & 15;
    const float* xp = x + (size_t)(rowbase + r) * D + c * 8;
    const float4 v0 = *(const float4*)(xp);
    const float4 v1 = *(const float4*)(xp + 4);

    // (b) B frags from wb: 1 KB/wave contiguous per load — coalesced
    const int lane = t & 63;
    const int wv = t >> 6;
    const int q = lane >> 4;
    const int nIdx = lane & 15;
    const int n0 = wv * 32;
    const short8* wbp = (const short8*)wb;
    short8 B[2][4];
    #pragma unroll
    for (int kt = 0; kt < 4; ++kt) {
        B[0][kt] = wbp[((wv * 4 + kt) * 2 + 0) * 64 + lane];
        B[1][kt] = wbp[((wv * 4 + kt) * 2 + 1) * 64 + lane];
    }

    // (a cont.) s1/s2 exact fp32 partials + bf16 pack to LDS
    {
        const float* w1 = w12 + c * 8;
        const float* w2 = w12 + D + c * 8;
        float p1 = v0.x * w1[0] + v0.y * w1[1] + v0.z * w1[2] + v0.w * w1[3]
                 + v1.x * w1[4] + v1.y * w1[5] + v1.z * w1[6] + v1.w * w1[7];
        float p2 = v0.x * w2[0] + v0.y * w2[1] + v0.z * w2[2] + v0.w * w2[3]
                 + v1.x * w2[4] + v1.y * w2[5] + v1.z * w2[6] + v1.w * w2[7];
        #pragma unroll
        for (int mask = 8; mask >= 1; mask >>= 1) {
            p1 += __shfl_xor(p1, mask);
            p2 += __shfl_xor(p2, mask);
        }
        if (c == 0) { s1[rowbase + r] = p1; s2[rowbase + r] = p2; }

        uint4 pk;
        pk.x = f2bf(v0.x) | (f2bf(v0.y) << 16);
        pk.y = f2bf(v0.z) | (f2bf(v0.w) << 16);
        pk.z = f2bf(v1.x) | (f2bf(v1.y) << 16);
        pk.w = f2bf(v1.z) | (f2bf(v1.w) << 16);
        *(uint4*)(lds + r * LDS_STRIDE + c * 16) = pk;
    }
    __syncthreads();

    // (c) A frags from LDS: A[m=nIdx][k=kt*32+q*8+j] -> byte kt*64 + q*16
    const unsigned char* ab = lds + nIdx * LDS_STRIDE + q * 16;
    const short8 A0 = *(const short8*)(ab);
    const short8 A1 = *(const short8*)(ab + 64);
    const short8 A2 = *(const short8*)(ab + 128);
    const short8 A3 = *(const short8*)(ab + 192);

    floatx4 acc0 = {0.f, 0.f, 0.f, 0.f};
    floatx4 acc1 = {0.f, 0.f, 0.f, 0.f};
    acc0 = __builtin_amdgcn_mfma_f32_16x16x32_bf16(A0, B[0][0], acc0, 0, 0, 0);
    acc1 = __builtin_amdgcn_mfma_f32_16x16x32_bf16(A0, B[1][0], acc1, 0, 0, 0);
    acc0 = __builtin_amdgcn_mfma_f32_16x16x32_bf16(A1, B[0][1], acc0, 0, 0, 0);
    acc1 = __builtin_amdgcn_mfma_f32_16x16x32_bf16(A1, B[1][1], acc1, 0, 0, 0);
    acc0 = __builtin_amdgcn_mfma_f32_16x16x32_bf16(A2, B[0][2], acc0, 0, 0, 0);
    acc1 = __builtin_amdgcn_mfma_f32_16x16x32_bf16(A2, B[1][2], acc1, 0, 0, 0);
    acc0 = __builtin_amdgcn_mfma_f32_16x16x32_bf16(A3, B[0][3], acc0, 0, 0, 0);
    acc1 = __builtin_amdgcn_mfma_f32_16x16x32_bf16(A3, B[1][3], acc1, 0, 0, 0);

    // epilogue: acc0 = even col n0+2*nIdx, acc1 = odd col n0+2*nIdx+1
    #pragma unroll
    for (int i = 0; i < 4; ++i) {
        const int row = rowbase + q * 4 + i;
        const unsigned int pk = f2bf(acc0[i]) | (f2bf(acc1[i]) << 16);
        *(unsigned int*)(hb + (size_t)row * D + n0 + 2 * nIdx) = pk;
    }

    // (d) deg + rank: exactly one edge per thread (3125*256 == N_EDGES)
    const int e = blockIdx.x * 256 + t;
    rank[e] = atomicAdd(&deg[ei[N_EDGES + e]], 1);
}

__device__ __forceinline__ void online_combine(float& m, float& s,
                                               float om, float os)
{
    float nm = fmaxf(m, om);
    s = s * __expf(m - nm) + os * __expf(om - nm);
    m = nm;
}

// ---- K2 (heterogeneous): block 0 = full exclusive scan of deg -> offs
// (1024 threads x 52 elems, int4, zero-padded so no guards); blocks 1..NB_MS
// = per-block online-softmax (m,s) over edges (runs concurrently with scan).
__global__ __launch_bounds__(1024) void k_mid(
    const int* __restrict__ ei, const float* __restrict__ s1,
    const float* __restrict__ s2, const int* __restrict__ deg,
    int* __restrict__ offs, float* __restrict__ bm, float* __restrict__ bs)
{
    const int t = threadIdx.x;
    const int lane = t & 63;
    const int wv = t >> 6;

    if (blockIdx.x == 0) {
        __shared__ int wsum[16];
        const int base = t * SCAN_PER;
        int4 v[13];
        const int4* dp = (const int4*)(deg + base);
        int s = 0;
        #pragma unroll
        for (int k = 0; k < 13; ++k) {
            v[k] = dp[k];
            s += v[k].x + v[k].y + v[k].z + v[k].w;
        }
        int inc = s;
        #pragma unroll
        for (int off = 1; off < 64; off <<= 1) {
            int u = __shfl_up(inc, off);
            if (lane >= off) inc += u;
        }
        if (lane == 63) wsum[wv] = inc;
        __syncthreads();
        if (wv == 0 && lane < 16) {
            int wval = wsum[lane];
            int winc = wval;
            #pragma unroll
            for (int off = 1; off < 16; off <<= 1) {
                int u = __shfl_up(winc, off);
                if (lane >= off) winc += u;
            }
            wsum[lane] = winc - wval;   // exclusive wave offset
        }
        __syncthreads();
        int run = wsum[wv] + (inc - s);  // exclusive thread prefix
        int4* op = (int4*)(offs + base);
        #pragma unroll
        for (int k = 0; k < 13; ++k) {
            int4 o;
            o.x = run;             run += v[k].x;
            o.y = run;             run += v[k].y;
            o.z = run;             run += v[k].z;
            o.w = run;             run += v[k].w;
            op[k] = o;
        }
        return;
    }

    const int e = (blockIdx.x - 1) * 1024 + t;
    float m = NEG_INF, s = 0.f;
    if (e < N_EDGES) {
        const int sN = ei[e];
        const int dN = ei[N_EDGES + e];
        float vv = s1[sN] + s2[dN];
        vv = vv > 0.f ? vv : ALPHA * vv;
        m = vv;
        s = 1.f;
    }
    #pragma unroll
    for (int off = 32; off >= 1; off >>= 1) {
        float om = __shfl_down(m, off);
        float os = __shfl_down(s, off);
        online_combine(m, s, om, os);
    }
    __shared__ float rm[16], rs[16];
    if (lane == 0) { rm[wv] = m; rs[wv] = s; }
    __syncthreads();
    if (t == 0) {
        #pragma unroll
        for (int w = 1; w < 16; ++w) online_combine(m, s, rm[w], rs[w]);
        bm[blockIdx.x - 1] = m;
        bs[blockIdx.x - 1] = s;
    }
}

// ---- K3: atomic-free CSR scatter (pos = offs[dst] + rank[e]); block 0
// additionally folds the NB_MS (m,s) partials -> global MZ.
__global__ __launch_bounds__(256) void k_post(
    const int* __restrict__ ei, const int* __restrict__ offs,
    const int* __restrict__ rank, unsigned int* __restrict__ csr,
    const float* __restrict__ bm, const float* __restrict__ bs,
    float* __restrict__ MZ)
{
    const int e = blockIdx.x * 256 + threadIdx.x;
    const int sN = ei[e];
    const int dN = ei[N_EDGES + e];
    csr[offs[dN] + rank[e]] = (unsigned int)sN;

    if (blockIdx.x == 0) {
        float m = NEG_INF, s = 0.f;
        for (int i = threadIdx.x; i < NB_MS; i += 256)
            online_combine(m, s, bm[i], bs[i]);
        #pragma unroll
        for (int off = 32; off >= 1; off >>= 1) {
            float om = __shfl_down(m, off);
            float os = __shfl_down(s, off);
            online_combine(m, s, om, os);
        }
        __shared__ float rm[4], rs[4];
        const int wid = threadIdx.x >> 6;
        if ((threadIdx.x & 63) == 0) { rm[wid] = m; rs[wid] = s; }
        __syncthreads();
        if (threadIdx.x == 0) {
            #pragma unroll
            for (int w = 1; w < 4; ++w) online_combine(m, s, rm[w], rs[w]);
            MZ[0] = m;
            MZ[1] = s;
        }
    }
}

// ---- K4: one wave per dst node; lane loads ONE csr src (coalesced),
// recomputes exact fp32 score + ONE exp; inner loop broadcasts (src, att)
// via uniform-index shfl with 8 independent hb row loads in flight.
__global__ __launch_bounds__(256) void k_gather(
    const unsigned int* __restrict__ csr, const int* __restrict__ offs,
    const float* __restrict__ s1, const float* __restrict__ s2,
    const unsigned short* __restrict__ hb, const float* __restrict__ MZ,
    float* __restrict__ out)
{
    const int node = (blockIdx.x * blockDim.x + threadIdx.x) >> 6;
    if (node >= N_NODES) return;
    const int lane = threadIdx.x & 63;
    const float M = MZ[0];
    const float invZ = 1.0f / MZ[1];
    const float s2n = s2[node];
    const int beg = offs[node];
    const int end = offs[node + 1];

    float a0 = 0.f, a1 = 0.f, b0 = 0.f, b1 = 0.f;
    float c0 = 0.f, c1 = 0.f, d0 = 0.f, d1 = 0.f;
    float e0 = 0.f, e1 = 0.f, f0 = 0.f, f1 = 0.f;
    float g0 = 0.f, g1 = 0.f, h0 = 0.f, h1 = 0.f;

    for (int cb = beg; cb < end; cb += 64) {
        const int n = min(64, end - cb);
        const int srcl = (cb + lane < end) ? (int)csr[cb + lane] : 0;
        float v = s1[srcl] + s2n;
        v = v > 0.f ? v : ALPHA * v;
        const float attl = __expf(v - M) * invZ;

        int j = 0;
        for (; j + 7 < n; j += 8) {
            const int i0 = __shfl(srcl, j);
            const int i1 = __shfl(srcl, j + 1);
            const int i2 = __shfl(srcl, j + 2);
            const int i3 = __shfl(srcl, j + 3);
            const int i4 = __shfl(srcl, j + 4);
            const int i5 = __shfl(srcl, j + 5);
            const int i6 = __shfl(srcl, j + 6);
            const int i7 = __shfl(srcl, j + 7);
            const float w0 = __shfl(attl, j);
            const float w1 = __shfl(attl, j + 1);
            const float w2 = __shfl(attl, j + 2);
            const float w3 = __shfl(attl, j + 3);
            const float w4 = __shfl(attl, j + 4);
            const float w5 = __shfl(attl, j + 5);
            const float w6 = __shfl(attl, j + 6);
            const float w7 = __shfl(attl, j + 7);
            const unsigned int u0 = *(const unsigned int*)(hb + (size_t)i0 * D + lane * 2);
            const unsigned int u1 = *(const unsigned int*)(hb + (size_t)i1 * D + lane * 2);
            const unsigned int u2 = *(const unsigned int*)(hb + (size_t)i2 * D + lane * 2);
            const unsigned int u3 = *(const unsigned int*)(hb + (size_t)i3 * D + lane * 2);
            const unsigned int u4 = *(const unsigned int*)(hb + (size_t)i4 * D + lane * 2);
            const unsigned int u5 = *(const unsigned int*)(hb + (size_t)i5 * D + lane * 2);
            const unsigned int u6 = *(const unsigned int*)(hb + (size_t)i6 * D + lane * 2);
            const unsigned int u7 = *(const unsigned int*)(hb + (size_t)i7 * D + lane * 2);
            a0 += w0 * bf_lo(u0); a1 += w0 * bf_hi(u0);
            b0 += w1 * bf_lo(u1); b1 += w1 * bf_hi(u1);
            c0 += w2 * bf_lo(u2); c1 += w2 * bf_hi(u2);
            d0 += w3 * bf_lo(u3); d1 += w3 * bf_hi(u3);
            e0 += w4 * bf_lo(u4); e1 += w4 * bf_hi(u4);
            f0 += w5 * bf_lo(u5); f1 += w5 * bf_hi(u5);
            g0 += w6 * bf_lo(u6); g1 += w6 * bf_hi(u6);
            h0 += w7 * bf_lo(u7); h1 += w7 * bf_hi(u7);
        }
        for (; j + 3 < n; j += 4) {
            const int i0 = __shfl(srcl, j);
            const int i1 = __shfl(srcl, j + 1);
            const int i2 = __shfl(srcl, j + 2);
            const int i3 = __shfl(srcl, j + 3);
            const float w0 = __shfl(attl, j);
            const float w1 = __shfl(attl, j + 1);
            const float w2 = __shfl(attl, j + 2);
            const float w3 = __shfl(attl, j + 3);
            const unsigned int u0 = *(const unsigned int*)(hb + (size_t)i0 * D + lane * 2);
            const unsigned int u1 = *(const unsigned int*)(hb + (size_t)i1 * D + lane * 2);
            const unsigned int u2 = *(const unsigned int*)(hb + (size_t)i2 * D + lane * 2);
            const unsigned int u3 = *(const unsigned int*)(hb + (size_t)i3 * D + lane * 2);
            a0 += w0 * bf_lo(u0); a1 += w0 * bf_hi(u0);
            b0 += w1 * bf_lo(u1); b1 += w1 * bf_hi(u1);
            c0 += w2 * bf_lo(u2); c1 += w2 * bf_hi(u2);
            d0 += w3 * bf_lo(u3); d1 += w3 * bf_hi(u3);
        }
        for (; j < n; ++j) {
            const int i0 = __shfl(srcl, j);
            const float w0 = __shfl(attl, j);
            const unsigned int u0 = *(const unsigned int*)(hb + (size_t)i0 * D + lane * 2);
            a0 += w0 * bf_lo(u0); a1 += w0 * bf_hi(u0);
        }
    }
    float2 r;
    r.x = ((a0 + b0) + (c0 + d0)) + ((e0 + f0) + (g0 + h0));
    r.y = ((a1 + b1) + (c1 + d1)) + ((e1 + f1) + (g1 + h1));
    *(float2*)(out + (size_t)node * D + lane * 2) = r;
}

extern "C" void kernel_launch(void* const* d_in, const int* in_sizes, int n_in,
                              void* d_out, int out_size, void* d_ws, size_t ws_size,
                              hipStream_t stream)
{
    const float* x = (const float*)d_in[0];
    const float* W = (const float*)d_in[1];
    const float* a = (const float*)d_in[2];
    const int* ei = (const int*)d_in[3];
    float* out = (float*)d_out;

    char* wsb = (char*)d_ws;
    unsigned int* csr = (unsigned int*)wsb;                        // 3.2 MB
    unsigned short* hb = (unsigned short*)(wsb + (size_t)N_EDGES * 4); // 12.8 MB
    unsigned short* wb = hb + (size_t)N_NODES * D;                 // 32 KB (16B aligned)
    int* rank     = (int*)(wb + 16384);                            // 3.2 MB
    float* s1     = (float*)(rank + N_EDGES);                      // 50,000
    float* s2     = s1 + N_NODES;                                  // 50,000
    int*   deg    = (int*)(s2 + N_NODES);                          // SCAN_PAD (zeroed)
    int*   offs   = deg + SCAN_PAD;                                // SCAN_PAD
    float* w12    = (float*)(offs + SCAN_PAD);                     // 256
    float* bm     = w12 + 2 * D;                                   // NB_MS
    float* bs     = bm + NB_MS;                                    // NB_MS
    float* MZ     = bs + NB_MS;                                    // 2

    k_prep<<<SCAN_PAD / 1024, 1024, 0, stream>>>(W, a, w12, wb, deg);
    k_fused<<<N_NODES / 16, 256, 0, stream>>>(x, w12, wb, ei, hb, s1, s2,
                                              deg, rank);
    k_mid<<<NB_MS + 1, 1024, 0, stream>>>(ei, s1, s2, deg, offs, bm, bs);
    k_post<<<KB_BLOCKS, 256, 0, stream>>>(ei, offs, rank, csr, bm, bs, MZ);
    k_gather<<<(N_NODES * 64 + 255) / 256, 256, 0, stream>>>(
        csr, offs, s1, s2, hb, MZ, out);
}

// Round 4
// 177.705 us; speedup vs baseline: 1.2607x; 1.0265x over previous
//
#include <hip/hip_runtime.h>
#include <hip/hip_bf16.h>

#define N_NODES 50000
#define N_EDGES 800000
#define D 128
#define ALPHA 0.2f
#define NEG_INF -1e30f

#define KB_BLOCKS 3125                 // 1 edge per thread, exact (3125*256)
#define LDS_STRIDE 272                 // 16 rows x (256B + 16B pad)

// scan geometry: one 1024-thread block scans deg alone, 52 elems/thread
#define SCAN_PER 52
#define SCAN_PAD (1024 * SCAN_PER)     // 53248 >= N_NODES, zero-padded

typedef __attribute__((ext_vector_type(8))) short short8;
typedef __attribute__((ext_vector_type(4))) float floatx4;

__device__ __forceinline__ unsigned int f2bf(float v)
{
    __hip_bfloat16 b = __float2bfloat16(v);
    return (unsigned int)*reinterpret_cast<unsigned short*>(&b);
}
__device__ __forceinline__ float bf_lo(unsigned int u)
{
    return __uint_as_float(u << 16);
}
__device__ __forceinline__ float bf_hi(unsigned int u)
{
    return __uint_as_float(u & 0xFFFF0000u);
}

// ---- K0: zero deg (padded, guard-free scan); blocks 0-3: w12 = {W@a1,W@a2}
// with COALESCED per-16-lane-group dots (R2 lesson: the old serial per-thread
// row-dot was 32k serialized L1 line fetches on one CU); blocks 4-19: pack W
// into the bf16 B-fragment layout wb (1 elem/thread).
__global__ __launch_bounds__(1024) void k_prep(
    const float* __restrict__ W, const float* __restrict__ a,
    float* __restrict__ w12, unsigned short* __restrict__ wb,
    int* __restrict__ deg)
{
    const int t = threadIdx.x;
    const int b = blockIdx.x;
    deg[b * 1024 + t] = 0;

    if (b < 4) {
        // 64 groups of 16 lanes per block; group g -> output (which=g>>7, r=g&127)
        const int g = b * 64 + (t >> 4);
        const int c = t & 15;
        const int which = g >> 7;
        const int r = g & 127;
        const float* wp = W + (size_t)r * D + c * 8;
        const float* ap = a + which * D + c * 8;
        const float4 u0 = *(const float4*)(wp);
        const float4 u1 = *(const float4*)(wp + 4);
        const float4 c0 = *(const float4*)(ap);
        const float4 c1 = *(const float4*)(ap + 4);
        float p = u0.x * c0.x + u0.y * c0.y + u0.z * c0.z + u0.w * c0.w
                + u1.x * c1.x + u1.y * c1.y + u1.z * c1.z + u1.w * c1.w;
        #pragma unroll
        for (int mask = 8; mask >= 1; mask >>= 1)
            p += __shfl_xor(p, mask);
        if (c == 0) w12[which * D + r] = p;
    } else if (b < 20) {
        // wb[f]: f = (((wv*4+kt)*2+half)*64+lane)*8+j
        const int f = (b - 4) * 1024 + t;
        const int j    = f & 7;
        const int lane = (f >> 3) & 63;
        const int half = (f >> 9) & 1;
        const int kt   = (f >> 10) & 3;
        const int wv   = f >> 12;
        const int q    = lane >> 4;
        const int nIdx = lane & 15;
        const float val =
            W[(size_t)(kt * 32 + q * 8 + j) * D + wv * 32 + 2 * nIdx + half];
        wb[f] = (unsigned short)f2bf(val);
    }
}

// ---- K0b: s1/s2 = x @ w12 directly (s1 = (x@W)@a1 == x@(W@a1)) — frees
// k_fused from the s-path and unblocks per-edge scores there.
// Same float4-dot + 16-lane xor-reduce pattern as before (bit-compatible).
__global__ __launch_bounds__(256) void k_sc(
    const float* __restrict__ x, const float* __restrict__ w12,
    float* __restrict__ s1, float* __restrict__ s2)
{
    const int t = threadIdx.x;
    const int r = t >> 4;
    const int c = t & 15;
    const int row = blockIdx.x * 16 + r;
    const float* xp = x + (size_t)row * D + c * 8;
    const float4 v0 = *(const float4*)(xp);
    const float4 v1 = *(const float4*)(xp + 4);
    const float* w1 = w12 + c * 8;
    const float* w2 = w12 + D + c * 8;
    float p1 = v0.x * w1[0] + v0.y * w1[1] + v0.z * w1[2] + v0.w * w1[3]
             + v1.x * w1[4] + v1.y * w1[5] + v1.z * w1[6] + v1.w * w1[7];
    float p2 = v0.x * w2[0] + v0.y * w2[1] + v0.z * w2[2] + v0.w * w2[3]
             + v1.x * w2[4] + v1.y * w2[5] + v1.z * w2[6] + v1.w * w2[7];
    #pragma unroll
    for (int mask = 8; mask >= 1; mask >>= 1) {
        p1 += __shfl_xor(p1, mask);
        p2 += __shfl_xor(p2, mask);
    }
    if (c == 0) { s1[row] = p1; s2[row] = p2; }
}

// ---- K1: fused per-16-row-tile kernel, 3125 blocks (exact):
//   edge loads issued FIRST (s1/s2 random gathers hide under MFMA staging)
//   (a) load x tile fp32, bf16 -> LDS
//   (b) B frags: 8x coalesced short8 loads from pre-packed wb (L2-resident)
//   (c) 8x MFMA 16x16x32 bf16, packed u32 stores of hb
//   (d) deg/rank atomic + per-edge score ve + block (max, sum-exp) partial
__global__ __launch_bounds__(256) void k_fused(
    const float* __restrict__ x, const unsigned short* __restrict__ wb,
    const int* __restrict__ ei, const float* __restrict__ s1,
    const float* __restrict__ s2, unsigned short* __restrict__ hb,
    int* __restrict__ deg, int* __restrict__ rank, float* __restrict__ ve,
    float* __restrict__ bm, float* __restrict__ bs)
{
    __shared__ unsigned char lds[16 * LDS_STRIDE];
    __shared__ float red[8];
    const int t = threadIdx.x;
    const int rowbase = blockIdx.x * 16;

    // edge loads first — consumed at the very end
    const int e = blockIdx.x * 256 + t;
    const int sN = ei[e];
    const int dN = ei[N_EDGES + e];
    const float s1g = s1[sN];
    const float s2g = s2[dN];

    // (a) stage x: thread t -> row r=t>>4, col-group c=t&15 (8 cols)
    const int r = t >> 4;
    const int c = t & 15;
    const float* xp = x + (size_t)(rowbase + r) * D + c * 8;
    const float4 v0 = *(const float4*)(xp);
    const float4 v1 = *(const float4*)(xp + 4);

    // (b) B frags from wb: 1 KB/wave contiguous per load — coalesced
    const int lane = t & 63;
    const int wv = t >> 6;
    const int q = lane >> 4;
    const int nIdx = lane & 15;
    const int n0 = wv * 32;
    const short8* wbp = (const short8*)wb;
    short8 B[2][4];
    #pragma unroll
    for (int kt = 0; kt < 4; ++kt) {
        B[0][kt] = wbp[((wv * 4 + kt) * 2 + 0) * 64 + lane];
        B[1][kt] = wbp[((wv * 4 + kt) * 2 + 1) * 64 + lane];
    }

    {
        uint4 pk;
        pk.x = f2bf(v0.x) | (f2bf(v0.y) << 16);
        pk.y = f2bf(v0.z) | (f2bf(v0.w) << 16);
        pk.z = f2bf(v1.x) | (f2bf(v1.y) << 16);
        pk.w = f2bf(v1.z) | (f2bf(v1.w) << 16);
        *(uint4*)(lds + r * LDS_STRIDE + c * 16) = pk;
    }
    __syncthreads();

    // (c) A frags from LDS: A[m=nIdx][k=kt*32+q*8+j] -> byte kt*64 + q*16
    const unsigned char* ab = lds + nIdx * LDS_STRIDE + q * 16;
    const short8 A0 = *(const short8*)(ab);
    const short8 A1 = *(const short8*)(ab + 64);
    const short8 A2 = *(const short8*)(ab + 128);
    const short8 A3 = *(const short8*)(ab + 192);

    floatx4 acc0 = {0.f, 0.f, 0.f, 0.f};
    floatx4 acc1 = {0.f, 0.f, 0.f, 0.f};
    acc0 = __builtin_amdgcn_mfma_f32_16x16x32_bf16(A0, B[0][0], acc0, 0, 0, 0);
    acc1 = __builtin_amdgcn_mfma_f32_16x16x32_bf16(A0, B[1][0], acc1, 0, 0, 0);
    acc0 = __builtin_amdgcn_mfma_f32_16x16x32_bf16(A1, B[0][1], acc0, 0, 0, 0);
    acc1 = __builtin_amdgcn_mfma_f32_16x16x32_bf16(A1, B[1][1], acc1, 0, 0, 0);
    acc0 = __builtin_amdgcn_mfma_f32_16x16x32_bf16(A2, B[0][2], acc0, 0, 0, 0);
    acc1 = __builtin_amdgcn_mfma_f32_16x16x32_bf16(A2, B[1][2], acc1, 0, 0, 0);
    acc0 = __builtin_amdgcn_mfma_f32_16x16x32_bf16(A3, B[0][3], acc0, 0, 0, 0);
    acc1 = __builtin_amdgcn_mfma_f32_16x16x32_bf16(A3, B[1][3], acc1, 0, 0, 0);

    // epilogue: acc0 = even col n0+2*nIdx, acc1 = odd col n0+2*nIdx+1
    #pragma unroll
    for (int i = 0; i < 4; ++i) {
        const int row = rowbase + q * 4 + i;
        const unsigned int pk = f2bf(acc0[i]) | (f2bf(acc1[i]) << 16);
        *(unsigned int*)(hb + (size_t)row * D + n0 + 2 * nIdx) = pk;
    }

    // (d) deg/rank + per-edge score + block softmax partial (two-phase)
    rank[e] = atomicAdd(&deg[dN], 1);
    float v = s1g + s2g;
    v = v > 0.f ? v : ALPHA * v;
    ve[e] = v;

    float m = v;
    #pragma unroll
    for (int mask = 32; mask >= 1; mask >>= 1)
        m = fmaxf(m, __shfl_xor(m, mask));
    if (lane == 0) red[wv] = m;
    __syncthreads();
    m = fmaxf(fmaxf(red[0], red[1]), fmaxf(red[2], red[3]));
    float sx = __expf(v - m);
    #pragma unroll
    for (int mask = 32; mask >= 1; mask >>= 1)
        sx += __shfl_xor(sx, mask);
    if (lane == 0) red[4 + wv] = sx;
    __syncthreads();
    if (t == 0) {
        bm[blockIdx.x] = m;
        bs[blockIdx.x] = red[4] + red[5] + red[6] + red[7];
    }
}

// ---- K2 (2 blocks): block 0 = full exclusive scan of deg -> offs
// (1024 threads x 52 elems, int4, zero-padded so no guards);
// block 1 = reduce 3125 (bm,bs) partials -> global MZ (two-phase).
__global__ __launch_bounds__(1024) void k_mid(
    const int* __restrict__ deg, int* __restrict__ offs,
    const float* __restrict__ bm, const float* __restrict__ bs,
    float* __restrict__ MZ)
{
    const int t = threadIdx.x;
    const int lane = t & 63;
    const int wv = t >> 6;

    if (blockIdx.x == 0) {
        __shared__ int wsum[16];
        const int base = t * SCAN_PER;
        int4 v[13];
        const int4* dp = (const int4*)(deg + base);
        int s = 0;
        #pragma unroll
        for (int k = 0; k < 13; ++k) {
            v[k] = dp[k];
            s += v[k].x + v[k].y + v[k].z + v[k].w;
        }
        int inc = s;
        #pragma unroll
        for (int off = 1; off < 64; off <<= 1) {
            int u = __shfl_up(inc, off);
            if (lane >= off) inc += u;
        }
        if (lane == 63) wsum[wv] = inc;
        __syncthreads();
        if (wv == 0 && lane < 16) {
            int wval = wsum[lane];
            int winc = wval;
            #pragma unroll
            for (int off = 1; off < 16; off <<= 1) {
                int u = __shfl_up(winc, off);
                if (lane >= off) winc += u;
            }
            wsum[lane] = winc - wval;   // exclusive wave offset
        }
        __syncthreads();
        int run = wsum[wv] + (inc - s);  // exclusive thread prefix
        int4* op = (int4*)(offs + base);
        #pragma unroll
        for (int k = 0; k < 13; ++k) {
            int4 o;
            o.x = run;             run += v[k].x;
            o.y = run;             run += v[k].y;
            o.z = run;             run += v[k].z;
            o.w = run;             run += v[k].w;
            op[k] = o;
        }
        return;
    }

    // block 1: MZ
    __shared__ float red[16];
    float m = NEG_INF;
    for (int i = t; i < KB_BLOCKS; i += 1024)
        m = fmaxf(m, bm[i]);
    #pragma unroll
    for (int mask = 32; mask >= 1; mask >>= 1)
        m = fmaxf(m, __shfl_xor(m, mask));
    if (lane == 0) red[wv] = m;
    __syncthreads();
    float M = red[0];
    #pragma unroll
    for (int w = 1; w < 16; ++w) M = fmaxf(M, red[w]);
    __syncthreads();
    float sx = 0.f;
    for (int i = t; i < KB_BLOCKS; i += 1024)
        sx += bs[i] * __expf(bm[i] - M);
    #pragma unroll
    for (int mask = 32; mask >= 1; mask >>= 1)
        sx += __shfl_xor(sx, mask);
    if (lane == 0) red[wv] = sx;
    __syncthreads();
    if (t == 0) {
        float Z = 0.f;
        #pragma unroll
        for (int w = 0; w < 16; ++w) Z += red[w];
        MZ[0] = M;
        MZ[1] = Z;
    }
}

// ---- K3: atomic-free CSR scatter of 8B records {src, ve} (pos =
// offs[dst] + rank[e]) — k_gather then needs NO random s-gathers.
__global__ __launch_bounds__(256) void k_post(
    const int* __restrict__ ei, const int* __restrict__ offs,
    const int* __restrict__ rank, const float* __restrict__ ve,
    uint2* __restrict__ csr64)
{
    const int e = blockIdx.x * 256 + threadIdx.x;
    const int sN = ei[e];
    const int dN = ei[N_EDGES + e];
    uint2 rec;
    rec.x = (unsigned int)sN;
    rec.y = __float_as_uint(ve[e]);
    csr64[offs[dN] + rank[e]] = rec;
}

// ---- K4: one wave per dst node; lane loads ONE 8B csr record (coalesced),
// ONE exp; inner loop broadcasts (src, att) via shfl with 8 independent hb
// row loads in flight.
__global__ __launch_bounds__(256) void k_gather(
    const uint2* __restrict__ csr64, const int* __restrict__ offs,
    const unsigned short* __restrict__ hb, const float* __restrict__ MZ,
    float* __restrict__ out)
{
    const int node = (blockIdx.x * blockDim.x + threadIdx.x) >> 6;
    if (node >= N_NODES) return;
    const int lane = threadIdx.x & 63;
    const float M = MZ[0];
    const float invZ = 1.0f / MZ[1];
    const int beg = offs[node];
    const int end = offs[node + 1];

    float a0 = 0.f, a1 = 0.f, b0 = 0.f, b1 = 0.f;
    float c0 = 0.f, c1 = 0.f, d0 = 0.f, d1 = 0.f;
    float e0 = 0.f, e1 = 0.f, f0 = 0.f, f1 = 0.f;
    float g0 = 0.f, g1 = 0.f, h0 = 0.f, h1 = 0.f;

    for (int cb = beg; cb < end; cb += 64) {
        const int n = min(64, end - cb);
        uint2 rec;
        if (cb + lane < end) {
            rec = csr64[cb + lane];
        } else {
            rec.x = 0u;
            rec.y = 0xFF800000u;   // -inf -> att = 0
        }
        const int srcl = (int)rec.x;
        const float attl = __expf(__uint_as_float(rec.y) - M) * invZ;

        int j = 0;
        for (; j + 7 < n; j += 8) {
            const int i0 = __shfl(srcl, j);
            const int i1 = __shfl(srcl, j + 1);
            const int i2 = __shfl(srcl, j + 2);
            const int i3 = __shfl(srcl, j + 3);
            const int i4 = __shfl(srcl, j + 4);
            const int i5 = __shfl(srcl, j + 5);
            const int i6 = __shfl(srcl, j + 6);
            const int i7 = __shfl(srcl, j + 7);
            const float w0 = __shfl(attl, j);
            const float w1 = __shfl(attl, j + 1);
            const float w2 = __shfl(attl, j + 2);
            const float w3 = __shfl(attl, j + 3);
            const float w4 = __shfl(attl, j + 4);
            const float w5 = __shfl(attl, j + 5);
            const float w6 = __shfl(attl, j + 6);
            const float w7 = __shfl(attl, j + 7);
            const unsigned int u0 = *(const unsigned int*)(hb + (size_t)i0 * D + lane * 2);
            const unsigned int u1 = *(const unsigned int*)(hb + (size_t)i1 * D + lane * 2);
            const unsigned int u2 = *(const unsigned int*)(hb + (size_t)i2 * D + lane * 2);
            const unsigned int u3 = *(const unsigned int*)(hb + (size_t)i3 * D + lane * 2);
            const unsigned int u4 = *(const unsigned int*)(hb + (size_t)i4 * D + lane * 2);
            const unsigned int u5 = *(const unsigned int*)(hb + (size_t)i5 * D + lane * 2);
            const unsigned int u6 = *(const unsigned int*)(hb + (size_t)i6 * D + lane * 2);
            const unsigned int u7 = *(const unsigned int*)(hb + (size_t)i7 * D + lane * 2);
            a0 += w0 * bf_lo(u0); a1 += w0 * bf_hi(u0);
            b0 += w1 * bf_lo(u1); b1 += w1 * bf_hi(u1);
            c0 += w2 * bf_lo(u2); c1 += w2 * bf_hi(u2);
            d0 += w3 * bf_lo(u3); d1 += w3 * bf_hi(u3);
            e0 += w4 * bf_lo(u4); e1 += w4 * bf_hi(u4);
            f0 += w5 * bf_lo(u5); f1 += w5 * bf_hi(u5);
            g0 += w6 * bf_lo(u6); g1 += w6 * bf_hi(u6);
            h0 += w7 * bf_lo(u7); h1 += w7 * bf_hi(u7);
        }
        for (; j + 3 < n; j += 4) {
            const int i0 = __shfl(srcl, j);
            const int i1 = __shfl(srcl, j + 1);
            const int i2 = __shfl(srcl, j + 2);
            const int i3 = __shfl(srcl, j + 3);
            const float w0 = __shfl(attl, j);
            const float w1 = __shfl(attl, j + 1);
            const float w2 = __shfl(attl, j + 2);
            const float w3 = __shfl(attl, j + 3);
            const unsigned int u0 = *(const unsigned int*)(hb + (size_t)i0 * D + lane * 2);
            const unsigned int u1 = *(const unsigned int*)(hb + (size_t)i1 * D + lane * 2);
            const unsigned int u2 = *(const unsigned int*)(hb + (size_t)i2 * D + lane * 2);
            const unsigned int u3 = *(const unsigned int*)(hb + (size_t)i3 * D + lane * 2);
            a0 += w0 * bf_lo(u0); a1 += w0 * bf_hi(u0);
            b0 += w1 * bf_lo(u1); b1 += w1 * bf_hi(u1);
            c0 += w2 * bf_lo(u2); c1 += w2 * bf_hi(u2);
            d0 += w3 * bf_lo(u3); d1 += w3 * bf_hi(u3);
        }
        for (; j < n; ++j) {
            const int i0 = __shfl(srcl, j);
            const float w0 = __shfl(attl, j);
            const unsigned int u0 = *(const unsigned int*)(hb + (size_t)i0 * D + lane * 2);
            a0 += w0 * bf_lo(u0); a1 += w0 * bf_hi(u0);
        }
    }
    float2 r;
    r.x = ((a0 + b0) + (c0 + d0)) + ((e0 + f0) + (g0 + h0));
    r.y = ((a1 + b1) + (c1 + d1)) + ((e1 + f1) + (g1 + h1));
    *(float2*)(out + (size_t)node * D + lane * 2) = r;
}

extern "C" void kernel_launch(void* const* d_in, const int* in_sizes, int n_in,
                              void* d_out, int out_size, void* d_ws, size_t ws_size,
                              hipStream_t stream)
{
    const float* x = (const float*)d_in[0];
    const float* W = (const float*)d_in[1];
    const float* a = (const float*)d_in[2];
    const int* ei = (const int*)d_in[3];
    float* out = (float*)d_out;

    char* wsb = (char*)d_ws;
    uint2* csr64 = (uint2*)wsb;                                    // 6.4 MB
    unsigned short* hb = (unsigned short*)(wsb + (size_t)N_EDGES * 8); // 12.8 MB
    unsigned short* wb = hb + (size_t)N_NODES * D;                 // 32 KB
    int* rank     = (int*)(wb + 16384);                            // 3.2 MB
    float* ve     = (float*)(rank + N_EDGES);                      // 3.2 MB
    float* s1     = ve + N_EDGES;                                  // 200 KB
    float* s2     = s1 + N_NODES;                                  // 200 KB
    int*   deg    = (int*)(s2 + N_NODES);                          // SCAN_PAD (zeroed)
    int*   offs   = deg + SCAN_PAD;                                // SCAN_PAD
    float* w12    = (float*)(offs + SCAN_PAD);                     // 256
    float* bm     = w12 + 2 * D;                                   // 3125
    float* bs     = bm + KB_BLOCKS;                                // 3125
    float* MZ     = bs + KB_BLOCKS;                                // 2

    k_prep<<<SCAN_PAD / 1024, 1024, 0, stream>>>(W, a, w12, wb, deg);
    k_sc<<<N_NODES / 16, 256, 0, stream>>>(x, w12, s1, s2);
    k_fused<<<N_NODES / 16, 256, 0, stream>>>(x, wb, ei, s1, s2, hb,
                                              deg, rank, ve, bm, bs);
    k_mid<<<2, 1024, 0, stream>>>(deg, offs, bm, bs, MZ);
    k_post<<<KB_BLOCKS, 256, 0, stream>>>(ei, offs, rank, ve, csr64);
    k_gather<<<(N_NODES * 64 + 255) / 256, 256, 0, stream>>>(
        csr64, offs, hb, MZ, out);
}